// Round 21
// baseline (110.316 us; speedup 1.0000x reference)
//
#include <hip/hip_runtime.h>
#include <hip/hip_fp16.h>

#define HH 256
#define WW 256
#define CC 32
#define HWSZ (HH * WW)
#define IMGSZ (CC * HWSZ)
#define NIMG 8
#define EPSV 1e-8f
#define NCH (CC / 2)   // channels per lane (2-way channel split)

__device__ __forceinline__ void acc_pass1(const float v[3][6],
                                          float sq[3][6], float dotv[8][4])
{
#pragma unroll
    for (int r = 0; r < 3; ++r)
#pragma unroll
        for (int j = 0; j < 6; ++j) sq[r][j] = fmaf(v[r][j], v[r][j], sq[r][j]);
    int d = 0;
#pragma unroll
    for (int dyi = 0; dyi < 3; ++dyi)
#pragma unroll
        for (int dxi = 0; dxi < 3; ++dxi) {
            if (dyi == 1 && dxi == 1) continue;
#pragma unroll
            for (int i = 0; i < 4; ++i)
                dotv[d][i] = fmaf(v[1][i + 1], v[dyi][i + dxi], dotv[d][i]);
            ++d;
        }
}

__device__ __forceinline__ void acc_pass2(const float v[3][6],
                                          const float w[8][4], float o[4])
{
    int d = 0;
#pragma unroll
    for (int dyi = 0; dyi < 3; ++dyi)
#pragma unroll
        for (int dxi = 0; dxi < 3; ++dxi) {
            if (dyi == 1 && dxi == 1) continue;
#pragma unroll
            for (int i = 0; i < 4; ++i)
                o[i] = fmaf(w[d][i], v[dyi][i + dxi], o[i]);
            ++d;
        }
}

__device__ __forceinline__ void gload16(const void* g, void* l)
{
    __builtin_amdgcn_global_load_lds(
        (const __attribute__((address_space(1))) void*)g,
        (__attribute__((address_space(3))) void*)l, 16, 0, 0);
}

__device__ __forceinline__ float cvtlo(unsigned u)
{ return __half2float(__ushort_as_half((unsigned short)(u & 0xffffu))); }
__device__ __forceinline__ float cvthi(unsigned u)
{ return __half2float(__ushort_as_half((unsigned short)(u >> 16))); }
__device__ __forceinline__ unsigned pkh(float a, float b)
{
    return (unsigned)__half_as_ushort(__float2half_rn(a)) |
           ((unsigned)__half_as_ushort(__float2half_rn(b)) << 16);
}

#define WAITB(VM) { asm volatile("s_waitcnt vmcnt(" #VM ")" ::: "memory"); \
                    __builtin_amdgcn_s_barrier(); }

// ============ CONVERT: f32 -> fp16, pure streaming, no barriers ============
__global__ __launch_bounds__(256) void convert_kernel(const float4* __restrict__ in,
                                                      uint4* __restrict__ out)
{
    const size_t stride = (size_t)gridDim.x * blockDim.x;
    const size_t n8 = (size_t)NIMG * IMGSZ / 8;   // 8 floats per iter
    for (size_t i = (size_t)blockIdx.x * blockDim.x + threadIdx.x; i < n8; i += stride) {
        float4 a = in[2 * i];
        float4 b = in[2 * i + 1];
        uint4 o;
        o.x = pkh(a.x, a.y);
        o.y = pkh(a.z, a.w);
        o.z = pkh(b.x, b.y);
        o.w = pkh(b.z, b.w);
        out[i] = o;
    }
}

// ===================== STEPS: fp16 input, channel-PAIR per barrier ======
// (R18-proven: 3 pair-slots = 24 KB, one wait+barrier per 2 channels.)

#define STAGE_P(P) { \
    const int ps_ = ((P) % 3) * 8192; \
    gload16(gsrcH + (size_t)(2 * ((P) & 7)     + halfS * 16) * HWSZ, ldstH + ps_); \
    gload16(gsrcH + (size_t)(2 * ((P) & 7) + 1 + halfS * 16) * HWSZ, ldstH + ps_ + 4096); }

#define LOADV_H(SB, VV) { \
    const char* sp_ = slabb + (SB); \
    _Pragma("unroll") \
    for (int r_ = 0; r_ < 3; ++r_) { \
        uint2 b_ = *(const uint2*)(sp_ + bMH + r_ * 512); \
        float e_ = 0.f; \
        if (edge && eok) { \
            unsigned eu_ = *(const unsigned*)(sp_ + bEH + r_ * 512); \
            e_ = (tx == 31) ? cvtlo(eu_) : cvthi(eu_); \
        } \
        const unsigned lu32_ = __shfl_up(b_.y, 1); \
        const unsigned rd32_ = __shfl_down(b_.x, 1); \
        const bool ok_ = rowok[r_]; \
        VV[r_][0] = (ok_ && xl) ? ((tx == 0)  ? e_ : cvthi(lu32_)) : 0.f; \
        VV[r_][1] = ok_ ? cvtlo(b_.x) : 0.f; \
        VV[r_][2] = ok_ ? cvthi(b_.x) : 0.f; \
        VV[r_][3] = ok_ ? cvtlo(b_.y) : 0.f; \
        VV[r_][4] = ok_ ? cvthi(b_.y) : 0.f; \
        VV[r_][5] = (ok_ && xr) ? ((tx == 31) ? e_ : cvtlo(rd32_)) : 0.f; \
    } }

template <bool YEDGE, bool COMPUTE_NEXT>
__device__ __forceinline__ void steph_body(const unsigned short* __restrict__ F,
                                           unsigned short* __restrict__ Fn,
                                           float* __restrict__ simout,
                                           char* slabb, int b, int rowblk, int tid)
{
    const int wave = tid >> 6;
    const int lane = tid & 63;
    const int half = lane >> 5;
    const int tx   = lane & 31;
    const int y0   = rowblk * 2;
    const int y    = y0 + (wave >> 1);
    const int x0   = (wave & 1) * 128 + (tx << 2);
    const int c0   = half * NCH;

    const bool ym = YEDGE ? (y > 0) : true;
    const bool yp = YEDGE ? (y < HH - 1) : true;
    const bool xl = x0 > 0, xr = x0 < WW - 4;
    const bool rowok[3] = { ym, true, yp };
    const bool colok[6] = { xl, true, true, true, true, xr };

    const unsigned short* Fb = F + (size_t)b * IMGSZ;

    const int halfS = wave >> 1;
    const int rp    = wave & 1;
    int srow = y0 - 1 + 2 * rp;
    int dsh  = 0;
    if (YEDGE) {
        if (srow < 0)               { srow = 0;      dsh = 512;  }
        else if (srow + 1 > HH - 1) { srow = HH - 2; dsh = -512; }
    }
    const unsigned short* gsrcH = Fb + srow * WW + lane * 8;
    char* ldstH = slabb + halfS * 2048 + rp * 1024 + dsh;

    const int bMH = half * 2048 + (wave >> 1) * 512 + x0 * 2;
    const bool edge = (tx == 0) || (tx == 31);
    const bool eok  = (tx == 31) ? xr : xl;
    const int bEH   = (tx == 31) ? (bMH + 8) : (bMH - 4);

    float sq[3][6];
    float dotv[8][4];
#pragma unroll
    for (int r = 0; r < 3; ++r)
#pragma unroll
        for (int j = 0; j < 6; ++j) sq[r][j] = 0.f;
#pragma unroll
    for (int d = 0; d < 8; ++d)
#pragma unroll
        for (int i = 0; i < 4; ++i) dotv[d][i] = 0.f;

    STAGE_P(0) STAGE_P(1)

#pragma unroll 1
    for (int p = 0; p < (COMPUTE_NEXT ? 8 : 6); ++p) {
        WAITB(2)
        const int sb = (p % 3) * 8192;
        { float v[3][6]; LOADV_H(sb, v)        acc_pass1(v, sq, dotv); }
        { float v[3][6]; LOADV_H(sb + 4096, v) acc_pass1(v, sq, dotv); }
        STAGE_P(p + 2)
    }
    if (!COMPUTE_NEXT) {
        { WAITB(2) const int sb = 0;
          float v[3][6]; LOADV_H(sb, v)        acc_pass1(v, sq, dotv);
          { float u[3][6]; LOADV_H(sb + 4096, u) acc_pass1(u, sq, dotv); } }
        { WAITB(0) const int sb = 8192;
          float v[3][6]; LOADV_H(sb, v)        acc_pass1(v, sq, dotv);
          { float u[3][6]; LOADV_H(sb + 4096, u) acc_pass1(u, sq, dotv); } }
    }

#pragma unroll
    for (int r = 0; r < 3; ++r)
#pragma unroll
        for (int j = 0; j < 6; ++j) sq[r][j] += __shfl_xor(sq[r][j], 32);
#pragma unroll
    for (int d = 0; d < 8; ++d)
#pragma unroll
        for (int i = 0; i < 4; ++i) dotv[d][i] += __shfl_xor(dotv[d][i], 32);

    float nrm[3][6];
#pragma unroll
    for (int r = 0; r < 3; ++r)
#pragma unroll
        for (int j = 0; j < 6; ++j) nrm[r][j] = __builtin_amdgcn_sqrtf(sq[r][j]);

    float w[8][4];
    float simarr[4];
#pragma unroll
    for (int i = 0; i < 4; ++i) {
        float s[8];
        const float cn = nrm[1][i + 1];
        float tot = 0.f, cnt = 0.f;
        int d = 0;
#pragma unroll
        for (int dyi = 0; dyi < 3; ++dyi)
#pragma unroll
            for (int dxi = 0; dxi < 3; ++dxi) {
                if (dyi == 1 && dxi == 1) continue;
                const bool m = rowok[dyi] && colok[i + dxi];
                const float den = fmaxf(cn * nrm[dyi][i + dxi], EPSV);
                const float cs = dotv[d][i] * __builtin_amdgcn_rcpf(den);
                s[d] = m ? cs : 0.f;
                tot += s[d];
                cnt += m ? 1.f : 0.f;
                ++d;
            }
        simarr[i] = tot * __builtin_amdgcn_rcpf(cnt);
        if (COMPUTE_NEXT) {
            float mx = s[0];
#pragma unroll
            for (int d2 = 1; d2 < 8; ++d2) mx = fmaxf(mx, s[d2]);
            float wsum = 0.f;
#pragma unroll
            for (int d2 = 0; d2 < 8; ++d2) { w[d2][i] = __expf(s[d2] - mx); wsum += w[d2][i]; }
            const float inv = __builtin_amdgcn_rcpf(wsum);
#pragma unroll
            for (int d2 = 0; d2 < 8; ++d2) w[d2][i] *= inv;
        }
    }
    if (half == 0) {
        float4 simv = { simarr[0], simarr[1], simarr[2], simarr[3] };
        *reinterpret_cast<float4*>(simout + b * HWSZ + y * WW + x0) = simv;
    }

    if (COMPUTE_NEXT) {
        unsigned short* outp = Fn + (size_t)b * IMGSZ + (size_t)c0 * HWSZ + y * WW + x0;

#define PASS2_PAIR(P) { \
            const int sb_ = ((P) % 3) * 8192; \
            const int ch_ = 2 * ((P) & 7); \
            { float v[3][6]; LOADV_H(sb_, v) \
              float o[4] = { 0.f, 0.f, 0.f, 0.f }; acc_pass2(v, w, o); \
              uint2 ov; ov.x = pkh(o[0], o[1]); ov.y = pkh(o[2], o[3]); \
              *reinterpret_cast<uint2*>(outp + ch_ * HWSZ) = ov; } \
            { float v[3][6]; LOADV_H(sb_ + 4096, v) \
              float o[4] = { 0.f, 0.f, 0.f, 0.f }; acc_pass2(v, w, o); \
              uint2 ov; ov.x = pkh(o[0], o[1]); ov.y = pkh(o[2], o[3]); \
              *reinterpret_cast<uint2*>(outp + (ch_ + 1) * HWSZ) = ov; } }

        { WAITB(3) PASS2_PAIR(8) STAGE_P(10) }
#pragma unroll 1
        for (int p = 9; p < 14; ++p) {
            WAITB(4)
            PASS2_PAIR(p)
            STAGE_P(p + 2)
        }
        { WAITB(4) PASS2_PAIR(14) }
        { WAITB(2) PASS2_PAIR(15) }
#undef PASS2_PAIR
    }
}

template <bool COMPUTE_NEXT>
__global__ __launch_bounds__(256, 4) void steph_kernel(const unsigned short* __restrict__ F,
                                                       unsigned short* __restrict__ Fn,
                                                       float* __restrict__ simout)
{
    const int linear = blockIdx.y * (HH / 2) + blockIdx.x;
    const int remap  = (linear & 7) * 128 + (linear >> 3);
    const int b      = remap >> 7;
    const int rowblk = remap & 127;

    __shared__ float4 slabH[1536];   // 24 KB: 3 pair-slots

    if (rowblk != 0 && rowblk != 127)
        steph_body<false, COMPUTE_NEXT>(F, Fn, simout, (char*)slabH, b, rowblk, threadIdx.x);
    else
        steph_body<true,  COMPUTE_NEXT>(F, Fn, simout, (char*)slabH, b, rowblk, threadIdx.x);
}

// out[g][t][p] = 0.25 * sum_{i<4} sims[tt][4g+i][p], tt = {0,0,1,2}[t]
__global__ __launch_bounds__(256) void reduce_kernel(const float* __restrict__ sims,
                                                     float* __restrict__ out)
{
    const int idx = blockIdx.x * blockDim.x + threadIdx.x;
    const int p4 = idx & (HWSZ / 4 - 1);
    const int t  = (idx >> 14) & 3;
    const int g  = idx >> 16;
    const int tt = (t <= 1) ? 0 : (t - 1);
    const float4* s = reinterpret_cast<const float4*>(sims) +
                      (size_t)(tt * NIMG + g * 4) * (HWSZ / 4) + p4;
    float4 a = s[0];
    float4 b = s[HWSZ / 4];
    float4 c = s[2 * (HWSZ / 4)];
    float4 d = s[3 * (HWSZ / 4)];
    float4 o;
    o.x = 0.25f * (a.x + b.x + c.x + d.x);
    o.y = 0.25f * (a.y + b.y + c.y + d.y);
    o.z = 0.25f * (a.z + b.z + c.z + d.z);
    o.w = 0.25f * (a.w + b.w + c.w + d.w);
    reinterpret_cast<float4*>(out)[idx] = o;
}

extern "C" void kernel_launch(void* const* d_in, const int* in_sizes, int n_in,
                              void* d_out, int out_size, void* d_ws, size_t ws_size,
                              hipStream_t stream)
{
    const float* F0 = (const float*)d_in[0];
    unsigned short* F0h = (unsigned short*)d_ws;                 // 32 MB fp16
    unsigned short* F1h = F0h + (size_t)NIMG * IMGSZ;            // 32 MB fp16
    unsigned short* F2h = F1h + (size_t)NIMG * IMGSZ;            // 32 MB fp16
    float* sims = (float*)(F2h + (size_t)NIMG * IMGSZ);          // 6 MB f32

    dim3 block(256);
    dim3 grid(HH / 2, NIMG);

    hipLaunchKernelGGL(convert_kernel, dim3(2048), block, 0, stream,
                       (const float4*)F0, (uint4*)F0h);
    hipLaunchKernelGGL((steph_kernel<true>),  grid, block, 0, stream, F0h, F1h, sims);
    hipLaunchKernelGGL((steph_kernel<true>),  grid, block, 0, stream, F1h, F2h, sims + (size_t)NIMG * HWSZ);
    hipLaunchKernelGGL((steph_kernel<false>), grid, block, 0, stream, F2h, nullptr, sims + (size_t)2 * NIMG * HWSZ);

    hipLaunchKernelGGL(reduce_kernel, dim3((2 * 4 * HWSZ / 4) / 256), block, 0, stream,
                       sims, (float*)d_out);
}

// Round 22
// 110.104 us; speedup vs baseline: 1.0019x; 1.0019x over previous
//
#include <hip/hip_runtime.h>
#include <hip/hip_fp16.h>

#define HH 256
#define WW 256
#define CC 32
#define HWSZ (HH * WW)
#define IMGSZ (CC * HWSZ)
#define NIMG 8
#define EPSV 1e-8f
#define NCH (CC / 2)   // channels per lane (2-way channel split)

__device__ __forceinline__ void acc_pass1(const float v[3][6],
                                          float sq[3][6], float dotv[8][4])
{
#pragma unroll
    for (int r = 0; r < 3; ++r)
#pragma unroll
        for (int j = 0; j < 6; ++j) sq[r][j] = fmaf(v[r][j], v[r][j], sq[r][j]);
    int d = 0;
#pragma unroll
    for (int dyi = 0; dyi < 3; ++dyi)
#pragma unroll
        for (int dxi = 0; dxi < 3; ++dxi) {
            if (dyi == 1 && dxi == 1) continue;
#pragma unroll
            for (int i = 0; i < 4; ++i)
                dotv[d][i] = fmaf(v[1][i + 1], v[dyi][i + dxi], dotv[d][i]);
            ++d;
        }
}

__device__ __forceinline__ void acc_pass2(const float v[3][6],
                                          const float w[8][4], float o[4])
{
    int d = 0;
#pragma unroll
    for (int dyi = 0; dyi < 3; ++dyi)
#pragma unroll
        for (int dxi = 0; dxi < 3; ++dxi) {
            if (dyi == 1 && dxi == 1) continue;
#pragma unroll
            for (int i = 0; i < 4; ++i)
                o[i] = fmaf(w[d][i], v[dyi][i + dxi], o[i]);
            ++d;
        }
}

__device__ __forceinline__ void gload16(const void* g, void* l)
{
    __builtin_amdgcn_global_load_lds(
        (const __attribute__((address_space(1))) void*)g,
        (__attribute__((address_space(3))) void*)l, 16, 0, 0);
}

__device__ __forceinline__ float cvtlo(unsigned u)
{ return __half2float(__ushort_as_half((unsigned short)(u & 0xffffu))); }
__device__ __forceinline__ float cvthi(unsigned u)
{ return __half2float(__ushort_as_half((unsigned short)(u >> 16))); }
__device__ __forceinline__ unsigned pkh(float a, float b)
{
    return (unsigned)__half_as_ushort(__float2half_rn(a)) |
           ((unsigned)__half_as_ushort(__float2half_rn(b)) << 16);
}

#define WAITB(VM) { asm volatile("s_waitcnt vmcnt(" #VM ")" ::: "memory"); \
                    __builtin_amdgcn_s_barrier(); }

// ============ CONVERT: f32 -> fp16, XCD-ALIGNED with the consumer ==========
// Same grid + bijective remap as steph: block (b,rowblk) converts exactly the
// 2 rows its co-located steph consumer owns -> dirty fp16 lines land in the
// SAME XCD's L2 (producer/consumer L2 locality; cross-XCD dirty reads killed
// R20). Perfectly coalesced float2 loads / u32 stores, no LDS, no barriers.
__global__ __launch_bounds__(256) void convert_kernel(const float* __restrict__ F,
                                                      unsigned short* __restrict__ Fh)
{
    const int linear = blockIdx.y * (HH / 2) + blockIdx.x;   // 0..1023
    const int remap  = (linear & 7) * 128 + (linear >> 3);
    const int b      = remap >> 7;
    const int rowblk = remap & 127;
    const int y      = rowblk * 2 + (threadIdx.x >> 7);      // this thread's row
    const int xg     = threadIdx.x & 127;                    // float2 group

    const float* src = F + (size_t)b * IMGSZ + y * WW + xg * 2;
    unsigned* dst = (unsigned*)(Fh + (size_t)b * IMGSZ + y * WW) + xg;
#pragma unroll 4
    for (int ch = 0; ch < CC; ++ch) {
        float2 a = *reinterpret_cast<const float2*>(src + ch * HWSZ);
        dst[ch * (HWSZ / 2)] = pkh(a.x, a.y);
    }
}

// ===================== STEPS: fp16 input, channel-PAIR per barrier ======
// (R18-proven: 3 pair-slots = 24 KB, one wait+barrier per 2 channels.)

#define STAGE_P(P) { \
    const int ps_ = ((P) % 3) * 8192; \
    gload16(gsrcH + (size_t)(2 * ((P) & 7)     + halfS * 16) * HWSZ, ldstH + ps_); \
    gload16(gsrcH + (size_t)(2 * ((P) & 7) + 1 + halfS * 16) * HWSZ, ldstH + ps_ + 4096); }

#define LOADV_H(SB, VV) { \
    const char* sp_ = slabb + (SB); \
    _Pragma("unroll") \
    for (int r_ = 0; r_ < 3; ++r_) { \
        uint2 b_ = *(const uint2*)(sp_ + bMH + r_ * 512); \
        float e_ = 0.f; \
        if (edge && eok) { \
            unsigned eu_ = *(const unsigned*)(sp_ + bEH + r_ * 512); \
            e_ = (tx == 31) ? cvtlo(eu_) : cvthi(eu_); \
        } \
        const unsigned lu32_ = __shfl_up(b_.y, 1); \
        const unsigned rd32_ = __shfl_down(b_.x, 1); \
        const bool ok_ = rowok[r_]; \
        VV[r_][0] = (ok_ && xl) ? ((tx == 0)  ? e_ : cvthi(lu32_)) : 0.f; \
        VV[r_][1] = ok_ ? cvtlo(b_.x) : 0.f; \
        VV[r_][2] = ok_ ? cvthi(b_.x) : 0.f; \
        VV[r_][3] = ok_ ? cvtlo(b_.y) : 0.f; \
        VV[r_][4] = ok_ ? cvthi(b_.y) : 0.f; \
        VV[r_][5] = (ok_ && xr) ? ((tx == 31) ? e_ : cvtlo(rd32_)) : 0.f; \
    } }

template <bool YEDGE, bool COMPUTE_NEXT>
__device__ __forceinline__ void steph_body(const unsigned short* __restrict__ F,
                                           unsigned short* __restrict__ Fn,
                                           float* __restrict__ simout,
                                           char* slabb, int b, int rowblk, int tid)
{
    const int wave = tid >> 6;
    const int lane = tid & 63;
    const int half = lane >> 5;
    const int tx   = lane & 31;
    const int y0   = rowblk * 2;
    const int y    = y0 + (wave >> 1);
    const int x0   = (wave & 1) * 128 + (tx << 2);
    const int c0   = half * NCH;

    const bool ym = YEDGE ? (y > 0) : true;
    const bool yp = YEDGE ? (y < HH - 1) : true;
    const bool xl = x0 > 0, xr = x0 < WW - 4;
    const bool rowok[3] = { ym, true, yp };
    const bool colok[6] = { xl, true, true, true, true, xr };

    const unsigned short* Fb = F + (size_t)b * IMGSZ;

    const int halfS = wave >> 1;
    const int rp    = wave & 1;
    int srow = y0 - 1 + 2 * rp;
    int dsh  = 0;
    if (YEDGE) {
        if (srow < 0)               { srow = 0;      dsh = 512;  }
        else if (srow + 1 > HH - 1) { srow = HH - 2; dsh = -512; }
    }
    const unsigned short* gsrcH = Fb + srow * WW + lane * 8;
    char* ldstH = slabb + halfS * 2048 + rp * 1024 + dsh;

    const int bMH = half * 2048 + (wave >> 1) * 512 + x0 * 2;
    const bool edge = (tx == 0) || (tx == 31);
    const bool eok  = (tx == 31) ? xr : xl;
    const int bEH   = (tx == 31) ? (bMH + 8) : (bMH - 4);

    float sq[3][6];
    float dotv[8][4];
#pragma unroll
    for (int r = 0; r < 3; ++r)
#pragma unroll
        for (int j = 0; j < 6; ++j) sq[r][j] = 0.f;
#pragma unroll
    for (int d = 0; d < 8; ++d)
#pragma unroll
        for (int i = 0; i < 4; ++i) dotv[d][i] = 0.f;

    STAGE_P(0) STAGE_P(1)

#pragma unroll 1
    for (int p = 0; p < (COMPUTE_NEXT ? 8 : 6); ++p) {
        WAITB(2)
        const int sb = (p % 3) * 8192;
        { float v[3][6]; LOADV_H(sb, v)        acc_pass1(v, sq, dotv); }
        { float v[3][6]; LOADV_H(sb + 4096, v) acc_pass1(v, sq, dotv); }
        STAGE_P(p + 2)
    }
    if (!COMPUTE_NEXT) {
        { WAITB(2) const int sb = 0;
          float v[3][6]; LOADV_H(sb, v)        acc_pass1(v, sq, dotv);
          { float u[3][6]; LOADV_H(sb + 4096, u) acc_pass1(u, sq, dotv); } }
        { WAITB(0) const int sb = 8192;
          float v[3][6]; LOADV_H(sb, v)        acc_pass1(v, sq, dotv);
          { float u[3][6]; LOADV_H(sb + 4096, u) acc_pass1(u, sq, dotv); } }
    }

#pragma unroll
    for (int r = 0; r < 3; ++r)
#pragma unroll
        for (int j = 0; j < 6; ++j) sq[r][j] += __shfl_xor(sq[r][j], 32);
#pragma unroll
    for (int d = 0; d < 8; ++d)
#pragma unroll
        for (int i = 0; i < 4; ++i) dotv[d][i] += __shfl_xor(dotv[d][i], 32);

    float nrm[3][6];
#pragma unroll
    for (int r = 0; r < 3; ++r)
#pragma unroll
        for (int j = 0; j < 6; ++j) nrm[r][j] = __builtin_amdgcn_sqrtf(sq[r][j]);

    float w[8][4];
    float simarr[4];
#pragma unroll
    for (int i = 0; i < 4; ++i) {
        float s[8];
        const float cn = nrm[1][i + 1];
        float tot = 0.f, cnt = 0.f;
        int d = 0;
#pragma unroll
        for (int dyi = 0; dyi < 3; ++dyi)
#pragma unroll
            for (int dxi = 0; dxi < 3; ++dxi) {
                if (dyi == 1 && dxi == 1) continue;
                const bool m = rowok[dyi] && colok[i + dxi];
                const float den = fmaxf(cn * nrm[dyi][i + dxi], EPSV);
                const float cs = dotv[d][i] * __builtin_amdgcn_rcpf(den);
                s[d] = m ? cs : 0.f;
                tot += s[d];
                cnt += m ? 1.f : 0.f;
                ++d;
            }
        simarr[i] = tot * __builtin_amdgcn_rcpf(cnt);
        if (COMPUTE_NEXT) {
            float mx = s[0];
#pragma unroll
            for (int d2 = 1; d2 < 8; ++d2) mx = fmaxf(mx, s[d2]);
            float wsum = 0.f;
#pragma unroll
            for (int d2 = 0; d2 < 8; ++d2) { w[d2][i] = __expf(s[d2] - mx); wsum += w[d2][i]; }
            const float inv = __builtin_amdgcn_rcpf(wsum);
#pragma unroll
            for (int d2 = 0; d2 < 8; ++d2) w[d2][i] *= inv;
        }
    }
    if (half == 0) {
        float4 simv = { simarr[0], simarr[1], simarr[2], simarr[3] };
        *reinterpret_cast<float4*>(simout + b * HWSZ + y * WW + x0) = simv;
    }

    if (COMPUTE_NEXT) {
        unsigned short* outp = Fn + (size_t)b * IMGSZ + (size_t)c0 * HWSZ + y * WW + x0;

#define PASS2_PAIR(P) { \
            const int sb_ = ((P) % 3) * 8192; \
            const int ch_ = 2 * ((P) & 7); \
            { float v[3][6]; LOADV_H(sb_, v) \
              float o[4] = { 0.f, 0.f, 0.f, 0.f }; acc_pass2(v, w, o); \
              uint2 ov; ov.x = pkh(o[0], o[1]); ov.y = pkh(o[2], o[3]); \
              *reinterpret_cast<uint2*>(outp + ch_ * HWSZ) = ov; } \
            { float v[3][6]; LOADV_H(sb_ + 4096, v) \
              float o[4] = { 0.f, 0.f, 0.f, 0.f }; acc_pass2(v, w, o); \
              uint2 ov; ov.x = pkh(o[0], o[1]); ov.y = pkh(o[2], o[3]); \
              *reinterpret_cast<uint2*>(outp + (ch_ + 1) * HWSZ) = ov; } }

        { WAITB(3) PASS2_PAIR(8) STAGE_P(10) }
#pragma unroll 1
        for (int p = 9; p < 14; ++p) {
            WAITB(4)
            PASS2_PAIR(p)
            STAGE_P(p + 2)
        }
        { WAITB(4) PASS2_PAIR(14) }
        { WAITB(2) PASS2_PAIR(15) }
#undef PASS2_PAIR
    }
}

template <bool COMPUTE_NEXT>
__global__ __launch_bounds__(256, 4) void steph_kernel(const unsigned short* __restrict__ F,
                                                       unsigned short* __restrict__ Fn,
                                                       float* __restrict__ simout)
{
    const int linear = blockIdx.y * (HH / 2) + blockIdx.x;
    const int remap  = (linear & 7) * 128 + (linear >> 3);
    const int b      = remap >> 7;
    const int rowblk = remap & 127;

    __shared__ float4 slabH[1536];   // 24 KB: 3 pair-slots

    if (rowblk != 0 && rowblk != 127)
        steph_body<false, COMPUTE_NEXT>(F, Fn, simout, (char*)slabH, b, rowblk, threadIdx.x);
    else
        steph_body<true,  COMPUTE_NEXT>(F, Fn, simout, (char*)slabH, b, rowblk, threadIdx.x);
}

// out[g][t][p] = 0.25 * sum_{i<4} sims[tt][4g+i][p], tt = {0,0,1,2}[t]
__global__ __launch_bounds__(256) void reduce_kernel(const float* __restrict__ sims,
                                                     float* __restrict__ out)
{
    const int idx = blockIdx.x * blockDim.x + threadIdx.x;
    const int p4 = idx & (HWSZ / 4 - 1);
    const int t  = (idx >> 14) & 3;
    const int g  = idx >> 16;
    const int tt = (t <= 1) ? 0 : (t - 1);
    const float4* s = reinterpret_cast<const float4*>(sims) +
                      (size_t)(tt * NIMG + g * 4) * (HWSZ / 4) + p4;
    float4 a = s[0];
    float4 b = s[HWSZ / 4];
    float4 c = s[2 * (HWSZ / 4)];
    float4 d = s[3 * (HWSZ / 4)];
    float4 o;
    o.x = 0.25f * (a.x + b.x + c.x + d.x);
    o.y = 0.25f * (a.y + b.y + c.y + d.y);
    o.z = 0.25f * (a.z + b.z + c.z + d.z);
    o.w = 0.25f * (a.w + b.w + c.w + d.w);
    reinterpret_cast<float4*>(out)[idx] = o;
}

extern "C" void kernel_launch(void* const* d_in, const int* in_sizes, int n_in,
                              void* d_out, int out_size, void* d_ws, size_t ws_size,
                              hipStream_t stream)
{
    const float* F0 = (const float*)d_in[0];
    unsigned short* F0h = (unsigned short*)d_ws;                 // 32 MB fp16
    unsigned short* F1h = F0h + (size_t)NIMG * IMGSZ;            // 32 MB fp16
    unsigned short* F2h = F1h + (size_t)NIMG * IMGSZ;            // 32 MB fp16
    float* sims = (float*)(F2h + (size_t)NIMG * IMGSZ);          // 6 MB f32

    dim3 block(256);
    dim3 grid(HH / 2, NIMG);

    hipLaunchKernelGGL(convert_kernel, grid, block, 0, stream, F0, F0h);
    hipLaunchKernelGGL((steph_kernel<true>),  grid, block, 0, stream, F0h, F1h, sims);
    hipLaunchKernelGGL((steph_kernel<true>),  grid, block, 0, stream, F1h, F2h, sims + (size_t)NIMG * HWSZ);
    hipLaunchKernelGGL((steph_kernel<false>), grid, block, 0, stream, F2h, nullptr, sims + (size_t)2 * NIMG * HWSZ);

    hipLaunchKernelGGL(reduce_kernel, dim3((2 * 4 * HWSZ / 4) / 256), block, 0, stream,
                       sims, (float*)d_out);
}

// Round 23
// 96.198 us; speedup vs baseline: 1.1468x; 1.1446x over previous
//
#include <hip/hip_runtime.h>
#include <hip/hip_fp16.h>

#define HH 256
#define WW 256
#define CC 32
#define HWSZ (HH * WW)
#define IMGSZ (CC * HWSZ)
#define NIMG 8
#define EPSV 1e-8f
#define NCH (CC / 2)   // channels per lane (2-way channel split)

__device__ __forceinline__ void acc_pass1(const float v[3][6],
                                          float sq[3][6], float dotv[8][4])
{
#pragma unroll
    for (int r = 0; r < 3; ++r)
#pragma unroll
        for (int j = 0; j < 6; ++j) sq[r][j] = fmaf(v[r][j], v[r][j], sq[r][j]);
    int d = 0;
#pragma unroll
    for (int dyi = 0; dyi < 3; ++dyi)
#pragma unroll
        for (int dxi = 0; dxi < 3; ++dxi) {
            if (dyi == 1 && dxi == 1) continue;
#pragma unroll
            for (int i = 0; i < 4; ++i)
                dotv[d][i] = fmaf(v[1][i + 1], v[dyi][i + dxi], dotv[d][i]);
            ++d;
        }
}

__device__ __forceinline__ void acc_pass2(const float v[3][6],
                                          const float w[8][4], float o[4])
{
    int d = 0;
#pragma unroll
    for (int dyi = 0; dyi < 3; ++dyi)
#pragma unroll
        for (int dxi = 0; dxi < 3; ++dxi) {
            if (dyi == 1 && dxi == 1) continue;
#pragma unroll
            for (int i = 0; i < 4; ++i)
                o[i] = fmaf(w[d][i], v[dyi][i + dxi], o[i]);
            ++d;
        }
}

__device__ __forceinline__ void gload16(const void* g, void* l)
{
    __builtin_amdgcn_global_load_lds(
        (const __attribute__((address_space(1))) void*)g,
        (__attribute__((address_space(3))) void*)l, 16, 0, 0);
}

__device__ __forceinline__ float cvtlo(unsigned u)
{ return __half2float(__ushort_as_half((unsigned short)(u & 0xffffu))); }
__device__ __forceinline__ float cvthi(unsigned u)
{ return __half2float(__ushort_as_half((unsigned short)(u >> 16))); }
__device__ __forceinline__ unsigned pkh(float a, float b)
{
    return (unsigned)__half_as_ushort(__float2half_rn(a)) |
           ((unsigned)__half_as_ushort(__float2half_rn(b)) << 16);
}

#define WAITB(VM) { asm volatile("s_waitcnt vmcnt(" #VM ")" ::: "memory"); \
                    __builtin_amdgcn_s_barrier(); }

// ===================== STEP 1: f32 input -> fp16 output =====================
// 5 slabs (40 KB), stage distance 4. vmcnt derived from FIFO
// (loads+stores, issue order). R19-proven champion configuration.

#define STAGE(SLOT) { \
    const int ch_ = (SLOT) & 15; \
    const int bo_ = ((SLOT) % 5) * 8192; \
    gload16(gsrc0 + (size_t)ch_ * HWSZ,        ldst0 + bo_); \
    gload16(gsrc0 + (size_t)(ch_ + 16) * HWSZ, ldst0 + bo_ + 4096); }

#define LOADV(G, VV) { \
    const char* sp_ = slabb + ((G) % 5) * 8192; \
    _Pragma("unroll") \
    for (int r_ = 0; r_ < 3; ++r_) { \
        float4 m_ = *(const float4*)(sp_ + bM + r_ * 1024); \
        float e_ = 0.f; \
        if (edge) e_ = *(const float*)(sp_ + bE + r_ * 1024); \
        const float lu_ = __shfl_up(m_.w, 1); \
        const float rd_ = __shfl_down(m_.x, 1); \
        const bool ok_ = rowok[r_]; \
        VV[r_][0] = (ok_ && xl) ? ((tx == 0)  ? e_ : lu_) : 0.f; \
        VV[r_][1] = ok_ ? m_.x : 0.f; \
        VV[r_][2] = ok_ ? m_.y : 0.f; \
        VV[r_][3] = ok_ ? m_.z : 0.f; \
        VV[r_][4] = ok_ ? m_.w : 0.f; \
        VV[r_][5] = (ok_ && xr) ? ((tx == 31) ? e_ : rd_) : 0.f; \
    } }

#define P2STORE(G) { \
    float v[3][6]; LOADV(G, v) \
    float o[4] = { 0.f, 0.f, 0.f, 0.f }; acc_pass2(v, w, o); \
    uint2 ov; ov.x = pkh(o[0], o[1]); ov.y = pkh(o[2], o[3]); \
    *reinterpret_cast<uint2*>(outp + ((G) & 15) * HWSZ) = ov; }

template <bool YEDGE>
__device__ __forceinline__ void step1_body(const float* __restrict__ F,
                                           unsigned short* __restrict__ Fn,
                                           float* __restrict__ simout,
                                           char* slabb, int b, int rowblk, int tid)
{
    const int wave = tid >> 6;
    const int lane = tid & 63;
    const int half = lane >> 5;
    const int tx   = lane & 31;
    const int y0   = rowblk * 2;
    const int y    = y0 + (wave >> 1);
    const int x0   = (wave & 1) * 128 + (tx << 2);
    const int c0   = half * NCH;

    const bool ym = YEDGE ? (y > 0) : true;
    const bool yp = YEDGE ? (y < HH - 1) : true;
    const bool xl = x0 > 0, xr = x0 < WW - 4;
    const bool rowok[3] = { ym, true, yp };
    const bool colok[6] = { xl, true, true, true, true, xr };

    const float* Fb = F + (size_t)b * IMGSZ;
    int arow = y0 - 1 + wave;
    if (YEDGE) arow = arow < 0 ? 0 : (arow > HH - 1 ? HH - 1 : arow);
    const float* gsrc0 = Fb + arow * WW + (lane << 2);
    char* ldst0 = slabb + wave * 1024;

    const int rbase = half * 4096 + (wave >> 1) * 1024;
    const int bM = rbase + x0 * 4;
    const int bL = rbase + (xl ? x0 * 4 - 4 : 0);
    const int bR = rbase + (xr ? x0 * 4 + 16 : 1020);
    const bool edge = (tx == 0) || (tx == 31);
    const int bE = (tx == 31) ? bR : bL;

    float sq[3][6];
    float dotv[8][4];
#pragma unroll
    for (int r = 0; r < 3; ++r)
#pragma unroll
        for (int j = 0; j < 6; ++j) sq[r][j] = 0.f;
#pragma unroll
    for (int d = 0; d < 8; ++d)
#pragma unroll
        for (int i = 0; i < 4; ++i) dotv[d][i] = 0.f;

    STAGE(0) STAGE(1) STAGE(2) STAGE(3)

#pragma unroll 1
    for (int g = 0; g < 16; ++g) {
        WAITB(6)
        STAGE(g + 4)                   // slots 4..19; g=12..15 prefetch pass-2 ch 0..3
        float v[3][6];
        LOADV(g, v)
        acc_pass1(v, sq, dotv);
    }

#pragma unroll
    for (int r = 0; r < 3; ++r)
#pragma unroll
        for (int j = 0; j < 6; ++j) sq[r][j] += __shfl_xor(sq[r][j], 32);
#pragma unroll
    for (int d = 0; d < 8; ++d)
#pragma unroll
        for (int i = 0; i < 4; ++i) dotv[d][i] += __shfl_xor(dotv[d][i], 32);

    float nrm[3][6];
#pragma unroll
    for (int r = 0; r < 3; ++r)
#pragma unroll
        for (int j = 0; j < 6; ++j) nrm[r][j] = __builtin_amdgcn_sqrtf(sq[r][j]);

    float w[8][4];
    float simarr[4];
#pragma unroll
    for (int i = 0; i < 4; ++i) {
        float s[8];
        const float cn = nrm[1][i + 1];
        float tot = 0.f, cnt = 0.f;
        int d = 0;
#pragma unroll
        for (int dyi = 0; dyi < 3; ++dyi)
#pragma unroll
            for (int dxi = 0; dxi < 3; ++dxi) {
                if (dyi == 1 && dxi == 1) continue;
                const bool m = rowok[dyi] && colok[i + dxi];
                const float den = fmaxf(cn * nrm[dyi][i + dxi], EPSV);
                const float cs = dotv[d][i] * __builtin_amdgcn_rcpf(den);
                s[d] = m ? cs : 0.f;
                tot += s[d];
                cnt += m ? 1.f : 0.f;
                ++d;
            }
        simarr[i] = tot * __builtin_amdgcn_rcpf(cnt);
        {
            float mx = s[0];
#pragma unroll
            for (int d2 = 1; d2 < 8; ++d2) mx = fmaxf(mx, s[d2]);
            float wsum = 0.f;
#pragma unroll
            for (int d2 = 0; d2 < 8; ++d2) { w[d2][i] = __expf(s[d2] - mx); wsum += w[d2][i]; }
            const float inv = __builtin_amdgcn_rcpf(wsum);
#pragma unroll
            for (int d2 = 0; d2 < 8; ++d2) w[d2][i] *= inv;
        }
    }
    if (half == 0) {
        float4 simv = { simarr[0], simarr[1], simarr[2], simarr[3] };
        *reinterpret_cast<float4*>(simout + b * HWSZ + y * WW + x0) = simv;
    }

    // Pass 2: slots 16..31. vmcnt ramp 7/8/9 -> steady 10 -> peels 10/8/6/4
    // (exact FIFO counts incl. the sim-store and per-iter uint2 stores).
    {
        unsigned short* outp = Fn + (size_t)b * IMGSZ + (size_t)c0 * HWSZ + y * WW + x0;
        { WAITB(7)  STAGE(20) P2STORE(16) }
        { WAITB(8)  STAGE(21) P2STORE(17) }
        { WAITB(9)  STAGE(22) P2STORE(18) }
#pragma unroll 1
        for (int g = 19; g < 28; ++g) {
            WAITB(10)
            STAGE(g + 4)               // 23..31
            P2STORE(g)
        }
        { WAITB(10) P2STORE(28) }
        { WAITB(8)  P2STORE(29) }
        { WAITB(6)  P2STORE(30) }
        { WAITB(4)  P2STORE(31) }
    }
}

__global__ __launch_bounds__(256, 4) void step1_kernel(const float* __restrict__ F,
                                                       unsigned short* __restrict__ Fn,
                                                       float* __restrict__ simout)
{
    const int linear = blockIdx.y * (HH / 2) + blockIdx.x;
    const int remap  = (linear & 7) * 128 + (linear >> 3);
    const int b      = remap >> 7;
    const int rowblk = remap & 127;

    __shared__ float4 slab4[2560];   // 40 KB: 5 slabs

    if (rowblk != 0 && rowblk != 127)
        step1_body<false>(F, Fn, simout, (char*)slab4, b, rowblk, threadIdx.x);
    else
        step1_body<true>(F, Fn, simout, (char*)slab4, b, rowblk, threadIdx.x);
}

// ===================== STEPS 2,3: fp16 input, channel-PAIR per barrier ======
// (R18-proven: 3 pair-slots = 24 KB, one wait+barrier per 2 channels.)

#define STAGE_P(P) { \
    const int ps_ = ((P) % 3) * 8192; \
    gload16(gsrcH + (size_t)(2 * ((P) & 7)     + halfS * 16) * HWSZ, ldstH + ps_); \
    gload16(gsrcH + (size_t)(2 * ((P) & 7) + 1 + halfS * 16) * HWSZ, ldstH + ps_ + 4096); }

#define LOADV_H(SB, VV) { \
    const char* sp_ = slabb + (SB); \
    _Pragma("unroll") \
    for (int r_ = 0; r_ < 3; ++r_) { \
        uint2 b_ = *(const uint2*)(sp_ + bMH + r_ * 512); \
        float e_ = 0.f; \
        if (edge && eok) { \
            unsigned eu_ = *(const unsigned*)(sp_ + bEH + r_ * 512); \
            e_ = (tx == 31) ? cvtlo(eu_) : cvthi(eu_); \
        } \
        const unsigned lu32_ = __shfl_up(b_.y, 1); \
        const unsigned rd32_ = __shfl_down(b_.x, 1); \
        const bool ok_ = rowok[r_]; \
        VV[r_][0] = (ok_ && xl) ? ((tx == 0)  ? e_ : cvthi(lu32_)) : 0.f; \
        VV[r_][1] = ok_ ? cvtlo(b_.x) : 0.f; \
        VV[r_][2] = ok_ ? cvthi(b_.x) : 0.f; \
        VV[r_][3] = ok_ ? cvtlo(b_.y) : 0.f; \
        VV[r_][4] = ok_ ? cvthi(b_.y) : 0.f; \
        VV[r_][5] = (ok_ && xr) ? ((tx == 31) ? e_ : cvtlo(rd32_)) : 0.f; \
    } }

template <bool YEDGE, bool COMPUTE_NEXT>
__device__ __forceinline__ void steph_body(const unsigned short* __restrict__ F,
                                           unsigned short* __restrict__ Fn,
                                           float* __restrict__ simout,
                                           char* slabb, int b, int rowblk, int tid)
{
    const int wave = tid >> 6;
    const int lane = tid & 63;
    const int half = lane >> 5;
    const int tx   = lane & 31;
    const int y0   = rowblk * 2;
    const int y    = y0 + (wave >> 1);
    const int x0   = (wave & 1) * 128 + (tx << 2);
    const int c0   = half * NCH;

    const bool ym = YEDGE ? (y > 0) : true;
    const bool yp = YEDGE ? (y < HH - 1) : true;
    const bool xl = x0 > 0, xr = x0 < WW - 4;
    const bool rowok[3] = { ym, true, yp };
    const bool colok[6] = { xl, true, true, true, true, xr };

    const unsigned short* Fb = F + (size_t)b * IMGSZ;

    const int halfS = wave >> 1;
    const int rp    = wave & 1;
    int srow = y0 - 1 + 2 * rp;
    int dsh  = 0;
    if (YEDGE) {
        if (srow < 0)               { srow = 0;      dsh = 512;  }
        else if (srow + 1 > HH - 1) { srow = HH - 2; dsh = -512; }
    }
    const unsigned short* gsrcH = Fb + srow * WW + lane * 8;
    char* ldstH = slabb + halfS * 2048 + rp * 1024 + dsh;

    const int bMH = half * 2048 + (wave >> 1) * 512 + x0 * 2;
    const bool edge = (tx == 0) || (tx == 31);
    const bool eok  = (tx == 31) ? xr : xl;
    const int bEH   = (tx == 31) ? (bMH + 8) : (bMH - 4);

    float sq[3][6];
    float dotv[8][4];
#pragma unroll
    for (int r = 0; r < 3; ++r)
#pragma unroll
        for (int j = 0; j < 6; ++j) sq[r][j] = 0.f;
#pragma unroll
    for (int d = 0; d < 8; ++d)
#pragma unroll
        for (int i = 0; i < 4; ++i) dotv[d][i] = 0.f;

    STAGE_P(0) STAGE_P(1)

#pragma unroll 1
    for (int p = 0; p < (COMPUTE_NEXT ? 8 : 6); ++p) {
        WAITB(2)
        const int sb = (p % 3) * 8192;
        { float v[3][6]; LOADV_H(sb, v)        acc_pass1(v, sq, dotv); }
        { float v[3][6]; LOADV_H(sb + 4096, v) acc_pass1(v, sq, dotv); }
        STAGE_P(p + 2)
    }
    if (!COMPUTE_NEXT) {
        { WAITB(2) const int sb = 0;
          float v[3][6]; LOADV_H(sb, v)        acc_pass1(v, sq, dotv);
          { float u[3][6]; LOADV_H(sb + 4096, u) acc_pass1(u, sq, dotv); } }
        { WAITB(0) const int sb = 8192;
          float v[3][6]; LOADV_H(sb, v)        acc_pass1(v, sq, dotv);
          { float u[3][6]; LOADV_H(sb + 4096, u) acc_pass1(u, sq, dotv); } }
    }

#pragma unroll
    for (int r = 0; r < 3; ++r)
#pragma unroll
        for (int j = 0; j < 6; ++j) sq[r][j] += __shfl_xor(sq[r][j], 32);
#pragma unroll
    for (int d = 0; d < 8; ++d)
#pragma unroll
        for (int i = 0; i < 4; ++i) dotv[d][i] += __shfl_xor(dotv[d][i], 32);

    float nrm[3][6];
#pragma unroll
    for (int r = 0; r < 3; ++r)
#pragma unroll
        for (int j = 0; j < 6; ++j) nrm[r][j] = __builtin_amdgcn_sqrtf(sq[r][j]);

    float w[8][4];
    float simarr[4];
#pragma unroll
    for (int i = 0; i < 4; ++i) {
        float s[8];
        const float cn = nrm[1][i + 1];
        float tot = 0.f, cnt = 0.f;
        int d = 0;
#pragma unroll
        for (int dyi = 0; dyi < 3; ++dyi)
#pragma unroll
            for (int dxi = 0; dxi < 3; ++dxi) {
                if (dyi == 1 && dxi == 1) continue;
                const bool m = rowok[dyi] && colok[i + dxi];
                const float den = fmaxf(cn * nrm[dyi][i + dxi], EPSV);
                const float cs = dotv[d][i] * __builtin_amdgcn_rcpf(den);
                s[d] = m ? cs : 0.f;
                tot += s[d];
                cnt += m ? 1.f : 0.f;
                ++d;
            }
        simarr[i] = tot * __builtin_amdgcn_rcpf(cnt);
        if (COMPUTE_NEXT) {
            float mx = s[0];
#pragma unroll
            for (int d2 = 1; d2 < 8; ++d2) mx = fmaxf(mx, s[d2]);
            float wsum = 0.f;
#pragma unroll
            for (int d2 = 0; d2 < 8; ++d2) { w[d2][i] = __expf(s[d2] - mx); wsum += w[d2][i]; }
            const float inv = __builtin_amdgcn_rcpf(wsum);
#pragma unroll
            for (int d2 = 0; d2 < 8; ++d2) w[d2][i] *= inv;
        }
    }
    if (half == 0) {
        float4 simv = { simarr[0], simarr[1], simarr[2], simarr[3] };
        *reinterpret_cast<float4*>(simout + b * HWSZ + y * WW + x0) = simv;
    }

    if (COMPUTE_NEXT) {
        unsigned short* outp = Fn + (size_t)b * IMGSZ + (size_t)c0 * HWSZ + y * WW + x0;

#define PASS2_PAIR(P) { \
            const int sb_ = ((P) % 3) * 8192; \
            const int ch_ = 2 * ((P) & 7); \
            { float v[3][6]; LOADV_H(sb_, v) \
              float o[4] = { 0.f, 0.f, 0.f, 0.f }; acc_pass2(v, w, o); \
              uint2 ov; ov.x = pkh(o[0], o[1]); ov.y = pkh(o[2], o[3]); \
              *reinterpret_cast<uint2*>(outp + ch_ * HWSZ) = ov; } \
            { float v[3][6]; LOADV_H(sb_ + 4096, v) \
              float o[4] = { 0.f, 0.f, 0.f, 0.f }; acc_pass2(v, w, o); \
              uint2 ov; ov.x = pkh(o[0], o[1]); ov.y = pkh(o[2], o[3]); \
              *reinterpret_cast<uint2*>(outp + (ch_ + 1) * HWSZ) = ov; } }

        { WAITB(3) PASS2_PAIR(8) STAGE_P(10) }
#pragma unroll 1
        for (int p = 9; p < 14; ++p) {
            WAITB(4)
            PASS2_PAIR(p)
            STAGE_P(p + 2)
        }
        { WAITB(4) PASS2_PAIR(14) }
        { WAITB(2) PASS2_PAIR(15) }
#undef PASS2_PAIR
    }
}

template <bool COMPUTE_NEXT>
__global__ __launch_bounds__(256, 4) void steph_kernel(const unsigned short* __restrict__ F,
                                                       unsigned short* __restrict__ Fn,
                                                       float* __restrict__ simout)
{
    const int linear = blockIdx.y * (HH / 2) + blockIdx.x;
    const int remap  = (linear & 7) * 128 + (linear >> 3);
    const int b      = remap >> 7;
    const int rowblk = remap & 127;

    __shared__ float4 slabH[1536];   // 24 KB: 3 pair-slots

    if (rowblk != 0 && rowblk != 127)
        steph_body<false, COMPUTE_NEXT>(F, Fn, simout, (char*)slabH, b, rowblk, threadIdx.x);
    else
        steph_body<true,  COMPUTE_NEXT>(F, Fn, simout, (char*)slabH, b, rowblk, threadIdx.x);
}

// out[g][t][p] = 0.25 * sum_{i<4} sims[tt][4g+i][p], tt = {0,0,1,2}[t]
__global__ __launch_bounds__(256) void reduce_kernel(const float* __restrict__ sims,
                                                     float* __restrict__ out)
{
    const int idx = blockIdx.x * blockDim.x + threadIdx.x;
    const int p4 = idx & (HWSZ / 4 - 1);
    const int t  = (idx >> 14) & 3;
    const int g  = idx >> 16;
    const int tt = (t <= 1) ? 0 : (t - 1);
    const float4* s = reinterpret_cast<const float4*>(sims) +
                      (size_t)(tt * NIMG + g * 4) * (HWSZ / 4) + p4;
    float4 a = s[0];
    float4 b = s[HWSZ / 4];
    float4 c = s[2 * (HWSZ / 4)];
    float4 d = s[3 * (HWSZ / 4)];
    float4 o;
    o.x = 0.25f * (a.x + b.x + c.x + d.x);
    o.y = 0.25f * (a.y + b.y + c.y + d.y);
    o.z = 0.25f * (a.z + b.z + c.z + d.z);
    o.w = 0.25f * (a.w + b.w + c.w + d.w);
    reinterpret_cast<float4*>(out)[idx] = o;
}

extern "C" void kernel_launch(void* const* d_in, const int* in_sizes, int n_in,
                              void* d_out, int out_size, void* d_ws, size_t ws_size,
                              hipStream_t stream)
{
    const float* F0 = (const float*)d_in[0];
    unsigned short* F1h = (unsigned short*)d_ws;                 // 32 MB fp16
    unsigned short* F2h = F1h + (size_t)NIMG * IMGSZ;            // 32 MB fp16
    float* sims = (float*)(F2h + (size_t)NIMG * IMGSZ);          // 6 MB f32

    dim3 block(256);
    dim3 grid(HH / 2, NIMG);

    hipLaunchKernelGGL(step1_kernel,          grid, block, 0, stream, F0, F1h, sims);
    hipLaunchKernelGGL((steph_kernel<true>),  grid, block, 0, stream, F1h, F2h, sims + (size_t)NIMG * HWSZ);
    hipLaunchKernelGGL((steph_kernel<false>), grid, block, 0, stream, F2h, nullptr, sims + (size_t)2 * NIMG * HWSZ);

    hipLaunchKernelGGL(reduce_kernel, dim3((2 * 4 * HWSZ / 4) / 256), block, 0, stream,
                       sims, (float*)d_out);
}

// Round 24
// 88.592 us; speedup vs baseline: 1.2452x; 1.0859x over previous
//
#include <hip/hip_runtime.h>
#include <hip/hip_fp16.h>

#define HH 256
#define WW 256
#define CC 32
#define HWSZ (HH * WW)
#define IMGSZ (CC * HWSZ)
#define NIMG 8
#define EPSV 1e-8f
#define NCH (CC / 2)   // channels per lane (2-way channel split)

__device__ __forceinline__ void acc_pass1(const float v[3][6],
                                          float sq[3][6], float dotv[8][4])
{
#pragma unroll
    for (int r = 0; r < 3; ++r)
#pragma unroll
        for (int j = 0; j < 6; ++j) sq[r][j] = fmaf(v[r][j], v[r][j], sq[r][j]);
    int d = 0;
#pragma unroll
    for (int dyi = 0; dyi < 3; ++dyi)
#pragma unroll
        for (int dxi = 0; dxi < 3; ++dxi) {
            if (dyi == 1 && dxi == 1) continue;
#pragma unroll
            for (int i = 0; i < 4; ++i)
                dotv[d][i] = fmaf(v[1][i + 1], v[dyi][i + dxi], dotv[d][i]);
            ++d;
        }
}

__device__ __forceinline__ void acc_pass2(const float v[3][6],
                                          const float w[8][4], float o[4])
{
    int d = 0;
#pragma unroll
    for (int dyi = 0; dyi < 3; ++dyi)
#pragma unroll
        for (int dxi = 0; dxi < 3; ++dxi) {
            if (dyi == 1 && dxi == 1) continue;
#pragma unroll
            for (int i = 0; i < 4; ++i)
                o[i] = fmaf(w[d][i], v[dyi][i + dxi], o[i]);
            ++d;
        }
}

__device__ __forceinline__ void gload16(const void* g, void* l)
{
    __builtin_amdgcn_global_load_lds(
        (const __attribute__((address_space(1))) void*)g,
        (__attribute__((address_space(3))) void*)l, 16, 0, 0);
}

__device__ __forceinline__ float cvtlo(unsigned u)
{ return __half2float(__ushort_as_half((unsigned short)(u & 0xffffu))); }
__device__ __forceinline__ float cvthi(unsigned u)
{ return __half2float(__ushort_as_half((unsigned short)(u >> 16))); }
__device__ __forceinline__ float cvt16(unsigned short u)
{ return __half2float(__ushort_as_half(u)); }
__device__ __forceinline__ unsigned pkh(float a, float b)
{
    return (unsigned)__half_as_ushort(__float2half_rn(a)) |
           ((unsigned)__half_as_ushort(__float2half_rn(b)) << 16);
}

#define WAITB(VM) { asm volatile("s_waitcnt vmcnt(" #VM ")" ::: "memory"); \
                    __builtin_amdgcn_s_barrier(); }

// ===================== STEP 1: f32 input -> fp16 output =====================
// 5 slabs (40 KB), stage distance 4. vmcnt derived from FIFO
// (loads+stores, issue order). R19-proven champion configuration.

#define STAGE(SLOT) { \
    const int ch_ = (SLOT) & 15; \
    const int bo_ = ((SLOT) % 5) * 8192; \
    gload16(gsrc0 + (size_t)ch_ * HWSZ,        ldst0 + bo_); \
    gload16(gsrc0 + (size_t)(ch_ + 16) * HWSZ, ldst0 + bo_ + 4096); }

#define LOADV(G, VV) { \
    const char* sp_ = slabb + ((G) % 5) * 8192; \
    _Pragma("unroll") \
    for (int r_ = 0; r_ < 3; ++r_) { \
        float4 m_ = *(const float4*)(sp_ + bM + r_ * 1024); \
        float e_ = 0.f; \
        if (edge) e_ = *(const float*)(sp_ + bE + r_ * 1024); \
        const float lu_ = __shfl_up(m_.w, 1); \
        const float rd_ = __shfl_down(m_.x, 1); \
        const bool ok_ = rowok[r_]; \
        VV[r_][0] = (ok_ && xl) ? ((tx == 0)  ? e_ : lu_) : 0.f; \
        VV[r_][1] = ok_ ? m_.x : 0.f; \
        VV[r_][2] = ok_ ? m_.y : 0.f; \
        VV[r_][3] = ok_ ? m_.z : 0.f; \
        VV[r_][4] = ok_ ? m_.w : 0.f; \
        VV[r_][5] = (ok_ && xr) ? ((tx == 31) ? e_ : rd_) : 0.f; \
    } }

#define P2STORE(G) { \
    float v[3][6]; LOADV(G, v) \
    float o[4] = { 0.f, 0.f, 0.f, 0.f }; acc_pass2(v, w, o); \
    uint2 ov; ov.x = pkh(o[0], o[1]); ov.y = pkh(o[2], o[3]); \
    *reinterpret_cast<uint2*>(outp + ((G) & 15) * HWSZ) = ov; }

template <bool YEDGE>
__device__ __forceinline__ void step1_body(const float* __restrict__ F,
                                           unsigned short* __restrict__ Fn,
                                           float* __restrict__ simout,
                                           char* slabb, int b, int rowblk, int tid)
{
    const int wave = tid >> 6;
    const int lane = tid & 63;
    const int half = lane >> 5;
    const int tx   = lane & 31;
    const int y0   = rowblk * 2;
    const int y    = y0 + (wave >> 1);
    const int x0   = (wave & 1) * 128 + (tx << 2);
    const int c0   = half * NCH;

    const bool ym = YEDGE ? (y > 0) : true;
    const bool yp = YEDGE ? (y < HH - 1) : true;
    const bool xl = x0 > 0, xr = x0 < WW - 4;
    const bool rowok[3] = { ym, true, yp };
    const bool colok[6] = { xl, true, true, true, true, xr };

    const float* Fb = F + (size_t)b * IMGSZ;
    int arow = y0 - 1 + wave;
    if (YEDGE) arow = arow < 0 ? 0 : (arow > HH - 1 ? HH - 1 : arow);
    const float* gsrc0 = Fb + arow * WW + (lane << 2);
    char* ldst0 = slabb + wave * 1024;

    const int rbase = half * 4096 + (wave >> 1) * 1024;
    const int bM = rbase + x0 * 4;
    const int bL = rbase + (xl ? x0 * 4 - 4 : 0);
    const int bR = rbase + (xr ? x0 * 4 + 16 : 1020);
    const bool edge = (tx == 0) || (tx == 31);
    const int bE = (tx == 31) ? bR : bL;

    float sq[3][6];
    float dotv[8][4];
#pragma unroll
    for (int r = 0; r < 3; ++r)
#pragma unroll
        for (int j = 0; j < 6; ++j) sq[r][j] = 0.f;
#pragma unroll
    for (int d = 0; d < 8; ++d)
#pragma unroll
        for (int i = 0; i < 4; ++i) dotv[d][i] = 0.f;

    STAGE(0) STAGE(1) STAGE(2) STAGE(3)

#pragma unroll 1
    for (int g = 0; g < 16; ++g) {
        WAITB(6)
        STAGE(g + 4)                   // slots 4..19; g=12..15 prefetch pass-2 ch 0..3
        float v[3][6];
        LOADV(g, v)
        acc_pass1(v, sq, dotv);
    }

#pragma unroll
    for (int r = 0; r < 3; ++r)
#pragma unroll
        for (int j = 0; j < 6; ++j) sq[r][j] += __shfl_xor(sq[r][j], 32);
#pragma unroll
    for (int d = 0; d < 8; ++d)
#pragma unroll
        for (int i = 0; i < 4; ++i) dotv[d][i] += __shfl_xor(dotv[d][i], 32);

    float nrm[3][6];
#pragma unroll
    for (int r = 0; r < 3; ++r)
#pragma unroll
        for (int j = 0; j < 6; ++j) nrm[r][j] = __builtin_amdgcn_sqrtf(sq[r][j]);

    float w[8][4];
    float simarr[4];
#pragma unroll
    for (int i = 0; i < 4; ++i) {
        float s[8];
        const float cn = nrm[1][i + 1];
        float tot = 0.f, cnt = 0.f;
        int d = 0;
#pragma unroll
        for (int dyi = 0; dyi < 3; ++dyi)
#pragma unroll
            for (int dxi = 0; dxi < 3; ++dxi) {
                if (dyi == 1 && dxi == 1) continue;
                const bool m = rowok[dyi] && colok[i + dxi];
                const float den = fmaxf(cn * nrm[dyi][i + dxi], EPSV);
                const float cs = dotv[d][i] * __builtin_amdgcn_rcpf(den);
                s[d] = m ? cs : 0.f;
                tot += s[d];
                cnt += m ? 1.f : 0.f;
                ++d;
            }
        simarr[i] = tot * __builtin_amdgcn_rcpf(cnt);
        {
            float mx = s[0];
#pragma unroll
            for (int d2 = 1; d2 < 8; ++d2) mx = fmaxf(mx, s[d2]);
            float wsum = 0.f;
#pragma unroll
            for (int d2 = 0; d2 < 8; ++d2) { w[d2][i] = __expf(s[d2] - mx); wsum += w[d2][i]; }
            const float inv = __builtin_amdgcn_rcpf(wsum);
#pragma unroll
            for (int d2 = 0; d2 < 8; ++d2) w[d2][i] *= inv;
        }
    }
    if (half == 0) {
        float4 simv = { simarr[0], simarr[1], simarr[2], simarr[3] };
        *reinterpret_cast<float4*>(simout + b * HWSZ + y * WW + x0) = simv;
    }

    // Pass 2: slots 16..31. vmcnt ramp 7/8/9 -> steady 10 -> peels 10/8/6/4.
    {
        unsigned short* outp = Fn + (size_t)b * IMGSZ + (size_t)c0 * HWSZ + y * WW + x0;
        { WAITB(7)  STAGE(20) P2STORE(16) }
        { WAITB(8)  STAGE(21) P2STORE(17) }
        { WAITB(9)  STAGE(22) P2STORE(18) }
#pragma unroll 1
        for (int g = 19; g < 28; ++g) {
            WAITB(10)
            STAGE(g + 4)               // 23..31
            P2STORE(g)
        }
        { WAITB(10) P2STORE(28) }
        { WAITB(8)  P2STORE(29) }
        { WAITB(6)  P2STORE(30) }
        { WAITB(4)  P2STORE(31) }
    }
}

__global__ __launch_bounds__(256, 4) void step1_kernel(const float* __restrict__ F,
                                                       unsigned short* __restrict__ Fn,
                                                       float* __restrict__ simout)
{
    const int linear = blockIdx.y * (HH / 2) + blockIdx.x;
    const int remap  = (linear & 7) * 128 + (linear >> 3);
    const int b      = remap >> 7;
    const int rowblk = remap & 127;

    __shared__ float4 slab4[2560];   // 40 KB: 5 slabs

    if (rowblk != 0 && rowblk != 127)
        step1_body<false>(F, Fn, simout, (char*)slab4, b, rowblk, threadIdx.x);
    else
        step1_body<true>(F, Fn, simout, (char*)slab4, b, rowblk, threadIdx.x);
}

// ===================== STEPS 2,3: fp16 input, channel-PAIR per barrier ======
// (R18-proven schedule: 3 pair-slots = 24 KB, one wait+barrier per 2 channels.)
// NEW: x-halo via DIRECT unaligned ds_read_u16 at bMH-2 / bMH+8 instead of
// ds_bpermute shuffles. fp16 stride-8B lane addresses -> 2 lanes/bank = free
// (m136); removes the b64->shuffle dependency chain and all edge-lane selects.

#define STAGE_P(P) { \
    const int ps_ = ((P) % 3) * 8192; \
    gload16(gsrcH + (size_t)(2 * ((P) & 7)     + halfS * 16) * HWSZ, ldstH + ps_); \
    gload16(gsrcH + (size_t)(2 * ((P) & 7) + 1 + halfS * 16) * HWSZ, ldstH + ps_ + 4096); }

#define LOADV_H(SB, VV) { \
    const char* sp_ = slabb + (SB); \
    _Pragma("unroll") \
    for (int r_ = 0; r_ < 3; ++r_) { \
        uint2 b_ = *(const uint2*)(sp_ + bMH + r_ * 512); \
        unsigned short lo_ = *(const unsigned short*)(sp_ + bLo + r_ * 512); \
        unsigned short hi_ = *(const unsigned short*)(sp_ + bHi + r_ * 512); \
        const bool ok_ = rowok[r_]; \
        VV[r_][0] = (ok_ && xl) ? cvt16(lo_) : 0.f; \
        VV[r_][1] = ok_ ? cvtlo(b_.x) : 0.f; \
        VV[r_][2] = ok_ ? cvthi(b_.x) : 0.f; \
        VV[r_][3] = ok_ ? cvtlo(b_.y) : 0.f; \
        VV[r_][4] = ok_ ? cvthi(b_.y) : 0.f; \
        VV[r_][5] = (ok_ && xr) ? cvt16(hi_) : 0.f; \
    } }

template <bool YEDGE, bool COMPUTE_NEXT>
__device__ __forceinline__ void steph_body(const unsigned short* __restrict__ F,
                                           unsigned short* __restrict__ Fn,
                                           float* __restrict__ simout,
                                           char* slabb, int b, int rowblk, int tid)
{
    const int wave = tid >> 6;
    const int lane = tid & 63;
    const int half = lane >> 5;
    const int tx   = lane & 31;
    const int y0   = rowblk * 2;
    const int y    = y0 + (wave >> 1);
    const int x0   = (wave & 1) * 128 + (tx << 2);
    const int c0   = half * NCH;

    const bool ym = YEDGE ? (y > 0) : true;
    const bool yp = YEDGE ? (y < HH - 1) : true;
    const bool xl = x0 > 0, xr = x0 < WW - 4;
    const bool rowok[3] = { ym, true, yp };
    const bool colok[6] = { xl, true, true, true, true, xr };

    const unsigned short* Fb = F + (size_t)b * IMGSZ;

    const int halfS = wave >> 1;
    const int rp    = wave & 1;
    int srow = y0 - 1 + 2 * rp;
    int dsh  = 0;
    if (YEDGE) {
        if (srow < 0)               { srow = 0;      dsh = 512;  }
        else if (srow + 1 > HH - 1) { srow = HH - 2; dsh = -512; }
    }
    const unsigned short* gsrcH = Fb + srow * WW + lane * 8;
    char* ldstH = slabb + halfS * 2048 + rp * 1024 + dsh;

    // Direct-read window addresses: body uint2 at bMH; halo u16 at bMH-2 /
    // bMH+8 (clamped to bMH at the true image x-edge; masked by xl/xr anyway).
    const int bMH = half * 2048 + (wave >> 1) * 512 + x0 * 2;
    const int bLo = bMH + (xl ? -2 : 0);
    const int bHi = bMH + (xr ?  8 : 0);

    float sq[3][6];
    float dotv[8][4];
#pragma unroll
    for (int r = 0; r < 3; ++r)
#pragma unroll
        for (int j = 0; j < 6; ++j) sq[r][j] = 0.f;
#pragma unroll
    for (int d = 0; d < 8; ++d)
#pragma unroll
        for (int i = 0; i < 4; ++i) dotv[d][i] = 0.f;

    STAGE_P(0) STAGE_P(1)

#pragma unroll 1
    for (int p = 0; p < (COMPUTE_NEXT ? 8 : 6); ++p) {
        WAITB(2)
        const int sb = (p % 3) * 8192;
        { float v[3][6]; LOADV_H(sb, v)        acc_pass1(v, sq, dotv); }
        { float v[3][6]; LOADV_H(sb + 4096, v) acc_pass1(v, sq, dotv); }
        STAGE_P(p + 2)
    }
    if (!COMPUTE_NEXT) {
        { WAITB(2) const int sb = 0;
          float v[3][6]; LOADV_H(sb, v)        acc_pass1(v, sq, dotv);
          { float u[3][6]; LOADV_H(sb + 4096, u) acc_pass1(u, sq, dotv); } }
        { WAITB(0) const int sb = 8192;
          float v[3][6]; LOADV_H(sb, v)        acc_pass1(v, sq, dotv);
          { float u[3][6]; LOADV_H(sb + 4096, u) acc_pass1(u, sq, dotv); } }
    }

#pragma unroll
    for (int r = 0; r < 3; ++r)
#pragma unroll
        for (int j = 0; j < 6; ++j) sq[r][j] += __shfl_xor(sq[r][j], 32);
#pragma unroll
    for (int d = 0; d < 8; ++d)
#pragma unroll
        for (int i = 0; i < 4; ++i) dotv[d][i] += __shfl_xor(dotv[d][i], 32);

    float nrm[3][6];
#pragma unroll
    for (int r = 0; r < 3; ++r)
#pragma unroll
        for (int j = 0; j < 6; ++j) nrm[r][j] = __builtin_amdgcn_sqrtf(sq[r][j]);

    float w[8][4];
    float simarr[4];
#pragma unroll
    for (int i = 0; i < 4; ++i) {
        float s[8];
        const float cn = nrm[1][i + 1];
        float tot = 0.f, cnt = 0.f;
        int d = 0;
#pragma unroll
        for (int dyi = 0; dyi < 3; ++dyi)
#pragma unroll
            for (int dxi = 0; dxi < 3; ++dxi) {
                if (dyi == 1 && dxi == 1) continue;
                const bool m = rowok[dyi] && colok[i + dxi];
                const float den = fmaxf(cn * nrm[dyi][i + dxi], EPSV);
                const float cs = dotv[d][i] * __builtin_amdgcn_rcpf(den);
                s[d] = m ? cs : 0.f;
                tot += s[d];
                cnt += m ? 1.f : 0.f;
                ++d;
            }
        simarr[i] = tot * __builtin_amdgcn_rcpf(cnt);
        if (COMPUTE_NEXT) {
            float mx = s[0];
#pragma unroll
            for (int d2 = 1; d2 < 8; ++d2) mx = fmaxf(mx, s[d2]);
            float wsum = 0.f;
#pragma unroll
            for (int d2 = 0; d2 < 8; ++d2) { w[d2][i] = __expf(s[d2] - mx); wsum += w[d2][i]; }
            const float inv = __builtin_amdgcn_rcpf(wsum);
#pragma unroll
            for (int d2 = 0; d2 < 8; ++d2) w[d2][i] *= inv;
        }
    }
    if (half == 0) {
        float4 simv = { simarr[0], simarr[1], simarr[2], simarr[3] };
        *reinterpret_cast<float4*>(simout + b * HWSZ + y * WW + x0) = simv;
    }

    if (COMPUTE_NEXT) {
        unsigned short* outp = Fn + (size_t)b * IMGSZ + (size_t)c0 * HWSZ + y * WW + x0;

#define PASS2_PAIR(P) { \
            const int sb_ = ((P) % 3) * 8192; \
            const int ch_ = 2 * ((P) & 7); \
            { float v[3][6]; LOADV_H(sb_, v) \
              float o[4] = { 0.f, 0.f, 0.f, 0.f }; acc_pass2(v, w, o); \
              uint2 ov; ov.x = pkh(o[0], o[1]); ov.y = pkh(o[2], o[3]); \
              *reinterpret_cast<uint2*>(outp + ch_ * HWSZ) = ov; } \
            { float v[3][6]; LOADV_H(sb_ + 4096, v) \
              float o[4] = { 0.f, 0.f, 0.f, 0.f }; acc_pass2(v, w, o); \
              uint2 ov; ov.x = pkh(o[0], o[1]); ov.y = pkh(o[2], o[3]); \
              *reinterpret_cast<uint2*>(outp + (ch_ + 1) * HWSZ) = ov; } }

        { WAITB(3) PASS2_PAIR(8) STAGE_P(10) }
#pragma unroll 1
        for (int p = 9; p < 14; ++p) {
            WAITB(4)
            PASS2_PAIR(p)
            STAGE_P(p + 2)
        }
        { WAITB(4) PASS2_PAIR(14) }
        { WAITB(2) PASS2_PAIR(15) }
#undef PASS2_PAIR
    }
}

template <bool COMPUTE_NEXT>
__global__ __launch_bounds__(256, 4) void steph_kernel(const unsigned short* __restrict__ F,
                                                       unsigned short* __restrict__ Fn,
                                                       float* __restrict__ simout)
{
    const int linear = blockIdx.y * (HH / 2) + blockIdx.x;
    const int remap  = (linear & 7) * 128 + (linear >> 3);
    const int b      = remap >> 7;
    const int rowblk = remap & 127;

    __shared__ float4 slabH[1536];   // 24 KB: 3 pair-slots

    if (rowblk != 0 && rowblk != 127)
        steph_body<false, COMPUTE_NEXT>(F, Fn, simout, (char*)slabH, b, rowblk, threadIdx.x);
    else
        steph_body<true,  COMPUTE_NEXT>(F, Fn, simout, (char*)slabH, b, rowblk, threadIdx.x);
}

// out[g][t][p] = 0.25 * sum_{i<4} sims[tt][4g+i][p], tt = {0,0,1,2}[t]
__global__ __launch_bounds__(256) void reduce_kernel(const float* __restrict__ sims,
                                                     float* __restrict__ out)
{
    const int idx = blockIdx.x * blockDim.x + threadIdx.x;
    const int p4 = idx & (HWSZ / 4 - 1);
    const int t  = (idx >> 14) & 3;
    const int g  = idx >> 16;
    const int tt = (t <= 1) ? 0 : (t - 1);
    const float4* s = reinterpret_cast<const float4*>(sims) +
                      (size_t)(tt * NIMG + g * 4) * (HWSZ / 4) + p4;
    float4 a = s[0];
    float4 b = s[HWSZ / 4];
    float4 c = s[2 * (HWSZ / 4)];
    float4 d = s[3 * (HWSZ / 4)];
    float4 o;
    o.x = 0.25f * (a.x + b.x + c.x + d.x);
    o.y = 0.25f * (a.y + b.y + c.y + d.y);
    o.z = 0.25f * (a.z + b.z + c.z + d.z);
    o.w = 0.25f * (a.w + b.w + c.w + d.w);
    reinterpret_cast<float4*>(out)[idx] = o;
}

extern "C" void kernel_launch(void* const* d_in, const int* in_sizes, int n_in,
                              void* d_out, int out_size, void* d_ws, size_t ws_size,
                              hipStream_t stream)
{
    const float* F0 = (const float*)d_in[0];
    unsigned short* F1h = (unsigned short*)d_ws;                 // 32 MB fp16
    unsigned short* F2h = F1h + (size_t)NIMG * IMGSZ;            // 32 MB fp16
    float* sims = (float*)(F2h + (size_t)NIMG * IMGSZ);          // 6 MB f32

    dim3 block(256);
    dim3 grid(HH / 2, NIMG);

    hipLaunchKernelGGL(step1_kernel,          grid, block, 0, stream, F0, F1h, sims);
    hipLaunchKernelGGL((steph_kernel<true>),  grid, block, 0, stream, F1h, F2h, sims + (size_t)NIMG * HWSZ);
    hipLaunchKernelGGL((steph_kernel<false>), grid, block, 0, stream, F2h, nullptr, sims + (size_t)2 * NIMG * HWSZ);

    hipLaunchKernelGGL(reduce_kernel, dim3((2 * 4 * HWSZ / 4) / 256), block, 0, stream,
                       sims, (float*)d_out);
}